// Round 1
// baseline (127.254 us; speedup 1.0000x reference)
//
#include <hip/hip_runtime.h>
#include <hip/hip_bf16.h>

// YOLO loss, fused. Inputs (dict order):
// 0:x0 [1,255,64,64] f32   1:x1 [1,255,128,128] f32   2:x2 [1,255,256,256] f32
// 3:label_cls [3] i32      4:label_bbx [3,4] f32      5:pos_anc [3] i32
// 6:pos_x [3] i32          7:pos_y [3] i32
// 8:neg0 [12288] i32       9:neg1 [49152] i32        10:neg2 [196608] i32
// 11:scale0 [1] i32       12:scale1 [1] i32          13:scale2 [1] i32
// Output: 1 float (total loss).

#define NC 80

__device__ __forceinline__ float softplus_f(float x) {
    // numerically stable softplus: max(x,0) + log1p(exp(-|x|))
    return fmaxf(x, 0.0f) + log1pf(__expf(-fabsf(x)));
}

// ---------------------------------------------------------------------------
// Kernel 1: per-block partial (num, den) of the negative objectness loss.
// Blocks [0,16): scale 0 (gs=64); [16,80): scale 1 (gs=128); [80,336): scale 2.
// One thread per cell, 3 anchors per thread. Objectness channels: 4, 84, 164.
// ---------------------------------------------------------------------------
__global__ __launch_bounds__(256) void yolo_neg_partials(
    const float* __restrict__ x0, const float* __restrict__ x1,
    const float* __restrict__ x2,
    const int* __restrict__ n0, const int* __restrict__ n1,
    const int* __restrict__ n2,
    float* __restrict__ ws /* [336][2] */)
{
    const int b = blockIdx.x;
    const int t = threadIdx.x;

    const float* __restrict__ x;
    const int* __restrict__ neg;
    int gs, cell;
    if (b < 16)      { x = x0; neg = n0; gs = 64;  cell = b * 256 + t; }
    else if (b < 80) { x = x1; neg = n1; gs = 128; cell = (b - 16) * 256 + t; }
    else             { x = x2; neg = n2; gs = 256; cell = (b - 80) * 256 + t; }
    const int gs2 = gs * gs;

    float num = 0.0f, den = 0.0f;
#pragma unroll
    for (int a = 0; a < 3; ++a) {
        // coalesced: lane t reads plane offset `cell` of channel (4 + 80a)
        float y = x[(4 + NC * a) * gs2 + cell];
        float m = (neg[cell * 3 + a] == 0) ? 1.0f : 0.0f;
        num += softplus_f(y) * m;
        den += m;
    }

    // wave (64-lane) reduce, then cross-wave via LDS
#pragma unroll
    for (int off = 32; off > 0; off >>= 1) {
        num += __shfl_down(num, off);
        den += __shfl_down(den, off);
    }
    __shared__ float s[8];
    const int wave = t >> 6;
    if ((t & 63) == 0) { s[wave * 2] = num; s[wave * 2 + 1] = den; }
    __syncthreads();
    if (t == 0) {
        ws[b * 2]     = s[0] + s[2] + s[4] + s[6];
        ws[b * 2 + 1] = s[1] + s[3] + s[5] + s[7];
    }
}

// ---------------------------------------------------------------------------
// Kernel 2: reduce partials per scale + positive-box terms, write scalar loss.
// Threads 0..254: (box j = t/85, channel c = t%85) — one scattered load each.
// Thread 255: sum_j num_j/den_j.
// ---------------------------------------------------------------------------
__global__ __launch_bounds__(256) void yolo_finalize(
    const float* __restrict__ x0, const float* __restrict__ x1,
    const float* __restrict__ x2,
    const int* __restrict__ label_cls, const float* __restrict__ label_bbx,
    const int* __restrict__ pos_anc, const int* __restrict__ pos_x,
    const int* __restrict__ pos_y,
    const int* __restrict__ sc0, const int* __restrict__ sc1,
    const int* __restrict__ sc2,
    const float* __restrict__ ws, float* __restrict__ out)
{
    __shared__ float s_num[3], s_den[3], s_total;
    const int t = threadIdx.x;
    if (t < 3) { s_num[t] = 0.0f; s_den[t] = 0.0f; }
    if (t == 3) s_total = 0.0f;
    __syncthreads();

    // fold 336 per-block partials into per-scale sums
    for (int p = t; p < 336; p += 256) {
        int sc = (p < 16) ? 0 : ((p < 80) ? 1 : 2);
        atomicAdd(&s_num[sc], ws[p * 2]);
        atomicAdd(&s_den[sc], ws[p * 2 + 1]);
    }
    __syncthreads();

    float contrib;
    if (t < 255) {
        const int j = t / 85;       // box index
        const int c = t % 85;       // channel within the anchor's 85-channel slab
        const int scl[3] = { sc0[0], sc1[0], sc2[0] };
        const int i = scl[j];       // pyramid level for this box (faithful to ref)
        const float* __restrict__ x = (i == 0) ? x0 : ((i == 1) ? x1 : x2);
        const int gs  = 64 << i;
        const int gs2 = gs * gs;
        const int a80 = pos_anc[j] * NC;
        const int cell = pos_y[j] * gs + pos_x[j];
        const float v = x[(a80 + c) * gs2 + cell];

        if (c == 4) {
            contrib = softplus_f(-v);                       // BCE(y_obj, 1)
        } else if (c >= 5) {
            float tv = ((c - 5) == label_cls[j]) ? v : 0.0f;
            contrib = (softplus_f(v) - tv) * (1.0f / 80.0f); // class BCE mean
        } else {
            // smooth-L1 bbox term (mean over 4, LAMB = 1)
            const float ANC[3][3][2] = {
                {{10.f, 13.f}, {16.f, 30.f}, {33.f, 23.f}},
                {{30.f, 61.f}, {62.f, 45.f}, {59.f, 119.f}},
                {{116.f, 90.f}, {156.f, 198.f}, {373.f, 326.f}}};
            const float a0 = ANC[j][i][0], a1 = ANC[j][i][1];
            const float b0 = label_bbx[4 * j], b1 = label_bbx[4 * j + 1];
            const float b2 = label_bbx[4 * j + 2], b3 = label_bbx[4 * j + 3];
            // NB: stride indexed by BOX index j (faithful to reference)
            const float strd = (float)(2048 / (64 << j));
            float tt;
            if (c == 0)      tt = ((b0 + b2) * 0.5f - (float)pos_x[j] * strd) / a0;
            else if (c == 1) tt = ((b1 + b3) * 0.5f - (float)pos_y[j] * strd) / a1;
            else if (c == 2) tt = logf((b2 - b0) / a0);
            else             tt = logf((b3 - b1) / a1);
            const float d = fabsf(v - tt);
            contrib = ((d < 1.0f) ? 0.5f * d * d : d - 0.5f) * 0.25f;
        }
    } else {
        // t == 255: per-scale mean negative losses
        contrib = s_num[0] / s_den[0] + s_num[1] / s_den[1] + s_num[2] / s_den[2];
    }

    atomicAdd(&s_total, contrib);
    __syncthreads();
    if (t == 0) out[0] = s_total;
}

extern "C" void kernel_launch(void* const* d_in, const int* in_sizes, int n_in,
                              void* d_out, int out_size, void* d_ws, size_t ws_size,
                              hipStream_t stream) {
    const float* x0 = (const float*)d_in[0];
    const float* x1 = (const float*)d_in[1];
    const float* x2 = (const float*)d_in[2];
    const int*   label_cls = (const int*)d_in[3];
    const float* label_bbx = (const float*)d_in[4];
    const int*   pos_anc = (const int*)d_in[5];
    const int*   pos_x   = (const int*)d_in[6];
    const int*   pos_y   = (const int*)d_in[7];
    const int*   n0 = (const int*)d_in[8];
    const int*   n1 = (const int*)d_in[9];
    const int*   n2 = (const int*)d_in[10];
    const int*   sc0 = (const int*)d_in[11];
    const int*   sc1 = (const int*)d_in[12];
    const int*   sc2 = (const int*)d_in[13];

    float* ws  = (float*)d_ws;   // 336*2 floats; fully written before read
    float* out = (float*)d_out;

    yolo_neg_partials<<<336, 256, 0, stream>>>(x0, x1, x2, n0, n1, n2, ws);
    yolo_finalize<<<1, 256, 0, stream>>>(x0, x1, x2, label_cls, label_bbx,
                                         pos_anc, pos_x, pos_y,
                                         sc0, sc1, sc2, ws, out);
}

// Round 2
// 127.105 us; speedup vs baseline: 1.0012x; 1.0012x over previous
//
#include <hip/hip_runtime.h>
#include <hip/hip_bf16.h>

// YOLO loss, single fused kernel. Inputs (dict order):
// 0:x0 [1,255,64,64] f32   1:x1 [1,255,128,128] f32   2:x2 [1,255,256,256] f32
// 3:label_cls [3] i32      4:label_bbx [3,4] f32      5:pos_anc [3] i32
// 6:pos_x [3] i32          7:pos_y [3] i32
// 8:neg0 [12288] i32       9:neg1 [49152] i32        10:neg2 [196608] i32
// 11..13: scale0..2 [1] i32
// Output: 1 float (total loss).
//
// Structure: 337 blocks. Blocks 0..335 = negative-loss producers (one thread
// per cell, 3 anchors each; block->scale: [0,16)=s0, [16,80)=s1, [80,336)=s2).
// Block 336 = consumer: computes the 255 positive-box terms (loads issued
// early to overlap producers), then spin-waits on per-producer magic flags
// (0x5A5A5A5A != 0xAA poison => no init kernel needed), reduces, writes out.
// Device-scope (AGENT) atomics handle cross-XCD visibility. Deadlock-free:
// 337 blocks x 4 waves << 2048-block co-residency capacity.

#define NC 80
#define NPROD 336
#define FLAG_MAGIC 0x5A5A5A5Au

__device__ __forceinline__ float softplus_f(float x) {
    // numerically stable softplus: max(x,0) + log1p(exp(-|x|))
    return fmaxf(x, 0.0f) + log1pf(__expf(-fabsf(x)));
}

__global__ __launch_bounds__(256) void yolo_fused(
    const float* __restrict__ x0, const float* __restrict__ x1,
    const float* __restrict__ x2,
    const int* __restrict__ label_cls, const float* __restrict__ label_bbx,
    const int* __restrict__ pos_anc, const int* __restrict__ pos_x,
    const int* __restrict__ pos_y,
    const int* __restrict__ n0, const int* __restrict__ n1,
    const int* __restrict__ n2,
    const int* __restrict__ sc0, const int* __restrict__ sc1,
    const int* __restrict__ sc2,
    float* __restrict__ ws,          // [NPROD][2] partials
    unsigned* __restrict__ flags,    // [NPROD] publish flags
    float* __restrict__ out)
{
    const int b = blockIdx.x;
    const int t = threadIdx.x;

    if (b < NPROD) {
        // ---------------- producer: negative objectness partials ----------
        const float* __restrict__ x;
        const int* __restrict__ neg;
        int gs, cell;
        if (b < 16)      { x = x0; neg = n0; gs = 64;  cell = b * 256 + t; }
        else if (b < 80) { x = x1; neg = n1; gs = 128; cell = (b - 16) * 256 + t; }
        else             { x = x2; neg = n2; gs = 256; cell = (b - 80) * 256 + t; }
        const int gs2 = gs * gs;

        float num = 0.0f, den = 0.0f;
#pragma unroll
        for (int a = 0; a < 3; ++a) {
            float y = x[(4 + NC * a) * gs2 + cell];   // coalesced plane read
            float m = (neg[cell * 3 + a] == 0) ? 1.0f : 0.0f;
            num += softplus_f(y) * m;
            den += m;
        }
#pragma unroll
        for (int off = 32; off > 0; off >>= 1) {
            num += __shfl_down(num, off);
            den += __shfl_down(den, off);
        }
        __shared__ float s[8];
        const int wave = t >> 6;
        if ((t & 63) == 0) { s[wave * 2] = num; s[wave * 2 + 1] = den; }
        __syncthreads();
        if (t == 0) {
            float nt = s[0] + s[2] + s[4] + s[6];
            float dt = s[1] + s[3] + s[5] + s[7];
            __hip_atomic_store(&ws[b * 2],     nt, __ATOMIC_RELAXED, __HIP_MEMORY_SCOPE_AGENT);
            __hip_atomic_store(&ws[b * 2 + 1], dt, __ATOMIC_RELAXED, __HIP_MEMORY_SCOPE_AGENT);
            __hip_atomic_store(&flags[b], FLAG_MAGIC, __ATOMIC_RELEASE, __HIP_MEMORY_SCOPE_AGENT);
        }
        return;
    }

    // ---------------- consumer block (b == NPROD) -------------------------
    __shared__ float s_num[3], s_den[3], s_total;
    if (t < 3) { s_num[t] = 0.0f; s_den[t] = 0.0f; }
    if (t == 3) s_total = 0.0f;

    // Positive-box terms first: the 255 scattered cold loads (~900 cyc HBM
    // latency each, issued in parallel across 4 waves) overlap the producers.
    float contrib = 0.0f;
    if (t < 255) {
        const int j = t / 85;       // box index
        const int c = t % 85;       // channel within the anchor's 85-slab
        const int scl[3] = { sc0[0], sc1[0], sc2[0] };
        const int i = scl[j];       // pyramid level (faithful to reference)
        const float* __restrict__ x = (i == 0) ? x0 : ((i == 1) ? x1 : x2);
        const int gs  = 64 << i;
        const int gs2 = gs * gs;
        const int a80 = pos_anc[j] * NC;
        const int cell = pos_y[j] * gs + pos_x[j];
        const float v = x[(a80 + c) * gs2 + cell];

        if (c == 4) {
            contrib = softplus_f(-v);                        // BCE(y_obj, 1)
        } else if (c >= 5) {
            float tv = ((c - 5) == label_cls[j]) ? v : 0.0f;
            contrib = (softplus_f(v) - tv) * (1.0f / 80.0f); // class BCE mean
        } else {
            const float ANC[3][3][2] = {
                {{10.f, 13.f}, {16.f, 30.f}, {33.f, 23.f}},
                {{30.f, 61.f}, {62.f, 45.f}, {59.f, 119.f}},
                {{116.f, 90.f}, {156.f, 198.f}, {373.f, 326.f}}};
            const float a0 = ANC[j][i][0], a1 = ANC[j][i][1];
            const float b0 = label_bbx[4 * j], b1 = label_bbx[4 * j + 1];
            const float b2 = label_bbx[4 * j + 2], b3 = label_bbx[4 * j + 3];
            // NB: stride indexed by BOX index j (faithful to reference)
            const float strd = (float)(2048 / (64 << j));
            float tt;
            if (c == 0)      tt = ((b0 + b2) * 0.5f - (float)pos_x[j] * strd) / a0;
            else if (c == 1) tt = ((b1 + b3) * 0.5f - (float)pos_y[j] * strd) / a1;
            else if (c == 2) tt = logf((b2 - b0) / a0);
            else             tt = logf((b3 - b1) / a1);
            const float d = fabsf(v - tt);
            contrib = ((d < 1.0f) ? 0.5f * d * d : d - 0.5f) * 0.25f;
        }
    }
    __syncthreads();   // s_num/s_den zeros visible

    // Collect producer partials (thread t handles slots t, t+256).
    for (int p = t; p < NPROD; p += 256) {
        while (__hip_atomic_load(&flags[p], __ATOMIC_ACQUIRE, __HIP_MEMORY_SCOPE_AGENT)
               != FLAG_MAGIC) { /* spin */ }
        float nu = __hip_atomic_load(&ws[p * 2],     __ATOMIC_RELAXED, __HIP_MEMORY_SCOPE_AGENT);
        float de = __hip_atomic_load(&ws[p * 2 + 1], __ATOMIC_RELAXED, __HIP_MEMORY_SCOPE_AGENT);
        const int sc = (p < 16) ? 0 : ((p < 80) ? 1 : 2);
        atomicAdd(&s_num[sc], nu);
        atomicAdd(&s_den[sc], de);
    }
    __syncthreads();

    if (t == 255)      // per-scale mean negative losses
        contrib = s_num[0] / s_den[0] + s_num[1] / s_den[1] + s_num[2] / s_den[2];

    atomicAdd(&s_total, contrib);
    __syncthreads();
    if (t == 0) out[0] = s_total;
}

extern "C" void kernel_launch(void* const* d_in, const int* in_sizes, int n_in,
                              void* d_out, int out_size, void* d_ws, size_t ws_size,
                              hipStream_t stream) {
    const float* x0 = (const float*)d_in[0];
    const float* x1 = (const float*)d_in[1];
    const float* x2 = (const float*)d_in[2];
    const int*   label_cls = (const int*)d_in[3];
    const float* label_bbx = (const float*)d_in[4];
    const int*   pos_anc = (const int*)d_in[5];
    const int*   pos_x   = (const int*)d_in[6];
    const int*   pos_y   = (const int*)d_in[7];
    const int*   n0 = (const int*)d_in[8];
    const int*   n1 = (const int*)d_in[9];
    const int*   n2 = (const int*)d_in[10];
    const int*   sc0 = (const int*)d_in[11];
    const int*   sc1 = (const int*)d_in[12];
    const int*   sc2 = (const int*)d_in[13];

    float*    ws    = (float*)d_ws;                    // [336][2] partials
    unsigned* flags = (unsigned*)(ws + 2 * NPROD);     // [336] magic flags
    float*    out   = (float*)d_out;

    yolo_fused<<<NPROD + 1, 256, 0, stream>>>(
        x0, x1, x2, label_cls, label_bbx, pos_anc, pos_x, pos_y,
        n0, n1, n2, sc0, sc1, sc2, ws, flags, out);
}